// Round 2
// baseline (500.908 us; speedup 1.0000x reference)
//
#include <hip/hip_runtime.h>
#include <hip/hip_bf16.h>

#define NN 6144
#define INPUT 1024
#define HID 256

using frag  = __attribute__((ext_vector_type(8))) short;   // 8 bf16
using f32x4 = __attribute__((ext_vector_type(4))) float;

static __device__ __forceinline__ unsigned short bf16u(float x) {
    unsigned u = __float_as_uint(x);
    u += 0x7fff + ((u >> 16) & 1);     // RNE
    return (unsigned short)(u >> 16);
}

// ---------------- convert X -> bf16 (row-major) ----------------
__global__ __launch_bounds__(256) void k_convert_x(const float* __restrict__ X,
                                                   unsigned short* __restrict__ Xb) {
    int t = blockIdx.x * 256 + threadIdx.x;          // one float4 per thread
    float4 v = reinterpret_cast<const float4*>(X)[t];
    ushort4 o;
    o.x = bf16u(v.x); o.y = bf16u(v.y); o.z = bf16u(v.z); o.w = bf16u(v.w);
    reinterpret_cast<ushort4*>(Xb)[t] = o;
}

// ---------------- convert W -> Wt bf16 transposed [HID][INPUT] ----------------
__global__ __launch_bounds__(256) void k_convert_w(const float* __restrict__ W,
                                                   unsigned short* __restrict__ Wt) {
    int t = blockIdx.x * 256 + threadIdx.x;          // t = n*1024 + k
    int n = t >> 10, k = t & 1023;
    Wt[t] = bf16u(W[k * HID + n]);
}

// ---------------- GEMM1: h = X @ W -> hT bf16, plus fused s1/s2 partials ----------------
// grid (96, 8); block 256 = 4 waves. Wave tile: M=16 (i0), N=32 (n0, 2 frags).
__global__ __launch_bounds__(256) void k_gemm1(const unsigned short* __restrict__ Xb,
                                               const unsigned short* __restrict__ Wt,
                                               const float* __restrict__ a_edge,
                                               unsigned short* __restrict__ hT,
                                               float* __restrict__ s1,
                                               float* __restrict__ s2) {
    int t = threadIdx.x;
    int w = t >> 6, l = t & 63, lm = l & 15, q = l >> 4;
    int i0 = blockIdx.x * 64 + w * 16;
    int n0 = blockIdx.y * 32;

    f32x4 acc0 = {}, acc1 = {};
    const unsigned short* arow  = Xb + (size_t)(i0 + lm) * INPUT + q * 8;
    const unsigned short* brow0 = Wt + (size_t)(n0 + lm) * INPUT + q * 8;
    const unsigned short* brow1 = brow0 + 16 * INPUT;

    for (int ks = 0; ks < INPUT; ks += 32) {
        frag a  = *reinterpret_cast<const frag*>(arow + ks);
        frag b0 = *reinterpret_cast<const frag*>(brow0 + ks);
        frag b1 = *reinterpret_cast<const frag*>(brow1 + ks);
        acc0 = __builtin_amdgcn_mfma_f32_16x16x32_bf16(a, b0, acc0, 0, 0, 0);
        acc1 = __builtin_amdgcn_mfma_f32_16x16x32_bf16(a, b1, acc1, 0, 0, 0);
    }

    // hT write: C/D layout col=lane&15 (n within frag), row=q*4+r (m)
    {
        ushort4 o;
        o.x = bf16u(acc0[0]); o.y = bf16u(acc0[1]); o.z = bf16u(acc0[2]); o.w = bf16u(acc0[3]);
        *reinterpret_cast<ushort4*>(hT + (size_t)(n0 + lm) * NN + i0 + q * 4) = o;
        o.x = bf16u(acc1[0]); o.y = bf16u(acc1[1]); o.z = bf16u(acc1[2]); o.w = bf16u(acc1[3]);
        *reinterpret_cast<ushort4*>(hT + (size_t)(n0 + 16 + lm) * NN + i0 + q * 4) = o;
    }

    // fused s1/s2 partials over this N-chunk (fp32 acc, same as separate svec on fp32 h)
    float a1v0 = a_edge[n0 + lm],        a1v1 = a_edge[n0 + 16 + lm];
    float a2v0 = a_edge[HID + n0 + lm],  a2v1 = a_edge[HID + n0 + 16 + lm];
#pragma unroll
    for (int r = 0; r < 4; r++) {
        float v1 = acc0[r] * a1v0 + acc1[r] * a1v1;
        float v2 = acc0[r] * a2v0 + acc1[r] * a2v1;
#pragma unroll
        for (int m = 1; m <= 8; m <<= 1) {
            v1 += __shfl_xor(v1, m);
            v2 += __shfl_xor(v2, m);
        }
        if (lm == 0) {
            atomicAdd(&s1[i0 + q * 4 + r], v1);
            atomicAdd(&s2[i0 + q * 4 + r], v2);
        }
    }
}

// ---------------- fused attention (no LDS, no barriers) ----------------
// grid (96, 16); block 256 = 4 independent waves. Wave: M=16 rows, N=256 (16 frags),
// j-chunk of 384 columns = 12 K-steps of 32.
// A-frag built per-lane: lane l holds A[m=l&15][k=(l>>4)*8+e] = p(row i0+m, col j0+it*32+q*8+e).
__global__ __launch_bounds__(256, 3) void k_attn(const int* __restrict__ adj,
                                                 const float* __restrict__ s1,
                                                 const float* __restrict__ s2,
                                                 const unsigned short* __restrict__ hT,
                                                 float* __restrict__ U,
                                                 float* __restrict__ denom) {
    int t = threadIdx.x;
    int w = t >> 6, l = t & 63, lm = l & 15, q = l >> 4;
    int i0 = (blockIdx.x * 4 + w) * 16;
    int j0 = blockIdx.y * 384;
    int row = i0 + lm;

    float s1v = s1[row];
    const int*   arow = adj + (size_t)row * NN + j0 + q * 8;
    const float* s2p  = s2 + j0 + q * 8;
    int boff = lm * NN + j0 + q * 8;     // hT element offset; + nt*16*NN per frag

    f32x4 acc[16] = {};
    float dsum = 0.f;

    for (int it = 0; it < 12; it++) {
        int4   a0 = *reinterpret_cast<const int4*>(arow);
        int4   a1 = *reinterpret_cast<const int4*>(arow + 4);
        float4 sa = *reinterpret_cast<const float4*>(s2p);
        float4 sb = *reinterpret_cast<const float4*>(s2p + 4);
        arow += 32; s2p += 32;

        float p0, p1, p2, p3, p4, p5, p6, p7, sc, wv;
        sc = s1v + sa.x; wv = fmaxf(sc, 0.2f * sc); p0 = a0.x ? __expf(wv) : 0.f;
        sc = s1v + sa.y; wv = fmaxf(sc, 0.2f * sc); p1 = a0.y ? __expf(wv) : 0.f;
        sc = s1v + sa.z; wv = fmaxf(sc, 0.2f * sc); p2 = a0.z ? __expf(wv) : 0.f;
        sc = s1v + sa.w; wv = fmaxf(sc, 0.2f * sc); p3 = a0.w ? __expf(wv) : 0.f;
        sc = s1v + sb.x; wv = fmaxf(sc, 0.2f * sc); p4 = a1.x ? __expf(wv) : 0.f;
        sc = s1v + sb.y; wv = fmaxf(sc, 0.2f * sc); p5 = a1.y ? __expf(wv) : 0.f;
        sc = s1v + sb.z; wv = fmaxf(sc, 0.2f * sc); p6 = a1.z ? __expf(wv) : 0.f;
        sc = s1v + sb.w; wv = fmaxf(sc, 0.2f * sc); p7 = a1.w ? __expf(wv) : 0.f;
        dsum += (p0 + p1) + (p2 + p3) + ((p4 + p5) + (p6 + p7));

        frag af;
        af[0] = (short)bf16u(p0); af[1] = (short)bf16u(p1);
        af[2] = (short)bf16u(p2); af[3] = (short)bf16u(p3);
        af[4] = (short)bf16u(p4); af[5] = (short)bf16u(p5);
        af[6] = (short)bf16u(p6); af[7] = (short)bf16u(p7);

#pragma unroll
        for (int nt = 0; nt < 16; nt++) {
            frag b = *reinterpret_cast<const frag*>(hT + boff + nt * 16 * NN);
            acc[nt] = __builtin_amdgcn_mfma_f32_16x16x32_bf16(af, b, acc[nt], 0, 0, 0);
        }
        boff += 32;
    }

    // denominator: lanes sharing lm (same row) across q cover all 32 cols/step
    float v = dsum;
    v += __shfl_xor(v, 16);
    v += __shfl_xor(v, 32);
    if (q == 0) atomicAdd(&denom[row], v);

    // U partials: C/D layout col=lane&15, row=q*4+r
#pragma unroll
    for (int nt = 0; nt < 16; nt++) {
        int n = nt * 16 + lm;
#pragma unroll
        for (int r = 0; r < 4; r++)
            atomicAdd(&U[(size_t)(i0 + q * 4 + r) * HID + n], acc[nt][r]);
    }
}

// ---------------- normalize: out = U / denom ----------------
__global__ __launch_bounds__(256) void k_norm(const float* __restrict__ U,
                                              const float* __restrict__ denom,
                                              float* __restrict__ out) {
    int i = blockIdx.x, t = threadIdx.x;
    float dn = denom[i];
    float u = U[(size_t)i * HID + t];
    out[(size_t)i * HID + t] = (dn != 0.f) ? u / dn : 0.f;
}

extern "C" void kernel_launch(void* const* d_in, const int* in_sizes, int n_in,
                              void* d_out, int out_size, void* d_ws, size_t ws_size,
                              hipStream_t stream) {
    const float* X      = (const float*)d_in[0];   // 6144x1024
    const float* W      = (const float*)d_in[1];   // 1024x256
    const float* a_edge = (const float*)d_in[2];   // 512
    const int*   adj    = (const int*)d_in[3];     // 6144x6144
    float* out = (float*)d_out;

    float* U     = (float*)d_ws;                        // NN*HID f32
    float* denom = U + (size_t)NN * HID;                // NN
    float* s1    = denom + NN;                          // NN
    float* s2    = s1 + NN;                             // NN
    unsigned short* hT = (unsigned short*)(s2 + NN);    // HID*NN bf16
    unsigned short* Xb = hT + (size_t)HID * NN;         // NN*INPUT bf16
    unsigned short* Wt = Xb + (size_t)NN * INPUT;       // HID*INPUT bf16

    hipMemsetAsync(U, 0, ((size_t)NN * HID + 3 * NN) * sizeof(float), stream);
    k_convert_x<<<NN * INPUT / 1024, 256, 0, stream>>>(X, Xb);
    k_convert_w<<<INPUT * HID / 256, 256, 0, stream>>>(W, Wt);
    k_gemm1<<<dim3(NN / 64, HID / 32), 256, 0, stream>>>(Xb, Wt, a_edge, hT, s1, s2);
    k_attn<<<dim3(NN / 64, 16), 256, 0, stream>>>(adj, s1, s2, hT, U, denom);
    k_norm<<<NN, 256, 0, stream>>>(U, denom, out);
}

// Round 3
// 307.547 us; speedup vs baseline: 1.6287x; 1.6287x over previous
//
#include <hip/hip_runtime.h>
#include <hip/hip_bf16.h>

#define NN 6144
#define INPUT 1024
#define HID 256

using frag  = __attribute__((ext_vector_type(8))) short;   // 8 bf16
using f32x4 = __attribute__((ext_vector_type(4))) float;

static __device__ __forceinline__ unsigned short bf16u(float x) {
    unsigned u = __float_as_uint(x);
    u += 0x7fff + ((u >> 16) & 1);     // RNE
    return (unsigned short)(u >> 16);
}

// ---------------- convert W -> Wt bf16 transposed [HID][INPUT] ----------------
__global__ __launch_bounds__(256) void k_convert_w(const float* __restrict__ W,
                                                   unsigned short* __restrict__ Wt) {
    int t = blockIdx.x * 256 + threadIdx.x;          // t = n*1024 + k
    int n = t >> 10, k = t & 1023;
    Wt[t] = bf16u(W[k * HID + n]);
}

// ---------------- GEMM1: hT = (X @ W)^T bf16, + fused s1/s2 ----------------
// grid (192, 4); block 256 = 4 waves. Block tile M=32 (i0), N=64 (n0); wave n-slice 16.
// X (f32) staged through LDS as bf16, barrier per 64-k chunk (16 chunks).
__global__ __launch_bounds__(256) void k_gemm1(const float* __restrict__ X,
                                               const unsigned short* __restrict__ Wt,
                                               const float* __restrict__ a_edge,
                                               unsigned short* __restrict__ hT,
                                               float* __restrict__ s1,
                                               float* __restrict__ s2) {
    __shared__ unsigned short A[2][32][72];   // padded: 72 ushorts = 144 B row stride
    int t = threadIdx.x;
    int m = t >> 3, cg = t & 7;               // builder: row m (0..31), col-group cg
    int i0 = blockIdx.x * 32, n0 = blockIdx.y * 64;
    int w = t >> 6, l = t & 63, lm = l & 15, q = l >> 4;
    int nw = n0 + w * 16;

    const float* xrow = X + (size_t)(i0 + m) * INPUT + cg * 8;
    const unsigned short* brow = Wt + (size_t)(nw + lm) * INPUT + q * 8;

    f32x4 acc0 = {}, acc1 = {};

    for (int c = 0; c < 16; c++) {
        int buf = c & 1;
        float4 xa = *reinterpret_cast<const float4*>(xrow + c * 64);
        float4 xb = *reinterpret_cast<const float4*>(xrow + c * 64 + 4);
        frag av;
        av[0] = (short)bf16u(xa.x); av[1] = (short)bf16u(xa.y);
        av[2] = (short)bf16u(xa.z); av[3] = (short)bf16u(xa.w);
        av[4] = (short)bf16u(xb.x); av[5] = (short)bf16u(xb.y);
        av[6] = (short)bf16u(xb.z); av[7] = (short)bf16u(xb.w);
        *reinterpret_cast<frag*>(&A[buf][m][cg * 8]) = av;

        __syncthreads();

#pragma unroll
        for (int kk = 0; kk < 2; kk++) {
            frag a0 = *reinterpret_cast<const frag*>(&A[buf][lm][kk * 32 + q * 8]);
            frag a1 = *reinterpret_cast<const frag*>(&A[buf][16 + lm][kk * 32 + q * 8]);
            frag b  = *reinterpret_cast<const frag*>(brow + c * 64 + kk * 32);
            acc0 = __builtin_amdgcn_mfma_f32_16x16x32_bf16(a0, b, acc0, 0, 0, 0);
            acc1 = __builtin_amdgcn_mfma_f32_16x16x32_bf16(a1, b, acc1, 0, 0, 0);
        }
    }

    // hT write: C/D layout col=lm (n), row=q*4+r (m within 16-half)
    ushort4 o;
    o.x = bf16u(acc0[0]); o.y = bf16u(acc0[1]); o.z = bf16u(acc0[2]); o.w = bf16u(acc0[3]);
    *reinterpret_cast<ushort4*>(hT + (size_t)(nw + lm) * NN + i0 + q * 4) = o;
    o.x = bf16u(acc1[0]); o.y = bf16u(acc1[1]); o.z = bf16u(acc1[2]); o.w = bf16u(acc1[3]);
    *reinterpret_cast<ushort4*>(hT + (size_t)(nw + lm) * NN + i0 + 16 + q * 4) = o;

    // fused s1/s2: reduce over the 16 n of this wave's slice, few atomics
    float a1v = a_edge[nw + lm], a2v = a_edge[HID + nw + lm];
#pragma unroll
    for (int h = 0; h < 2; h++) {
        const f32x4& ac = h ? acc1 : acc0;
#pragma unroll
        for (int r = 0; r < 4; r++) {
            float v1 = ac[r] * a1v, v2 = ac[r] * a2v;
            v1 += __shfl_xor(v1, 1); v2 += __shfl_xor(v2, 1);
            v1 += __shfl_xor(v1, 2); v2 += __shfl_xor(v2, 2);
            v1 += __shfl_xor(v1, 4); v2 += __shfl_xor(v2, 4);
            v1 += __shfl_xor(v1, 8); v2 += __shfl_xor(v2, 8);
            if (lm == 0) {
                atomicAdd(&s1[i0 + h * 16 + q * 4 + r], v1);
                atomicAdd(&s2[i0 + h * 16 + q * 4 + r], v2);
            }
        }
    }
}

// ---------------- fused attention ----------------
// grid (192, 4); block 256 = 4 waves. M=32 rows/block, j-quarter 1536 cols, 12 chunks of 128.
// P tile built in LDS (row-major, padded), one barrier per chunk, double-buffered.
// B-frags straight from hT (line-dense gather). Non-atomic partial outputs U4/denom4.
__global__ __launch_bounds__(256) void k_attn(const int* __restrict__ adj,
                                              const float* __restrict__ s1,
                                              const float* __restrict__ s2,
                                              const unsigned short* __restrict__ hT,
                                              float* __restrict__ U4,
                                              float* __restrict__ denom4) {
    __shared__ unsigned short P[2][32][136];   // 17408 B; 136 ushorts = 272 B row stride
    int t = threadIdx.x;
    int m = t >> 3, cg = t & 7;                // builder: row m (0..31)
    int i0 = blockIdx.x * 32;
    int q4 = blockIdx.y;
    int j0 = q4 * 1536;
    int w = t >> 6, l = t & 63, lm = l & 15, q = l >> 4;

    float s1v = s1[i0 + m];
    const int*   arow = adj + (size_t)(i0 + m) * NN + j0 + cg * 4;
    const float* s2p  = s2 + j0 + cg * 4;

    const unsigned short* brow[4];
#pragma unroll
    for (int nt = 0; nt < 4; nt++)
        brow[nt] = hT + (size_t)(w * 64 + nt * 16 + lm) * NN + j0 + q * 8;

    f32x4 acc[2][4] = {};
    float dsum = 0.f;

    for (int c = 0; c < 12; c++) {
        int buf = c & 1;
        int jc = c * 128;
        // ---- build P chunk: 4 passes, each instr-dense (8 rows x 32 contiguous cols) ----
#pragma unroll
        for (int p = 0; p < 4; p++) {
            int4   av = *reinterpret_cast<const int4*>(arow + jc + p * 32);
            float4 sv = *reinterpret_cast<const float4*>(s2p + jc + p * 32);
            float sc, wv, p0, p1, p2, p3;
            sc = s1v + sv.x; wv = fmaxf(sc, 0.2f * sc); p0 = av.x ? __expf(wv) : 0.f;
            sc = s1v + sv.y; wv = fmaxf(sc, 0.2f * sc); p1 = av.y ? __expf(wv) : 0.f;
            sc = s1v + sv.z; wv = fmaxf(sc, 0.2f * sc); p2 = av.z ? __expf(wv) : 0.f;
            sc = s1v + sv.w; wv = fmaxf(sc, 0.2f * sc); p3 = av.w ? __expf(wv) : 0.f;
            dsum += (p0 + p1) + (p2 + p3);
            ushort4 pk;
            pk.x = bf16u(p0); pk.y = bf16u(p1); pk.z = bf16u(p2); pk.w = bf16u(p3);
            *reinterpret_cast<ushort4*>(&P[buf][m][p * 32 + cg * 4]) = pk;
        }
        __syncthreads();
        // ---- consume: 4 k-steps x (2 A-halves x 4 B-frags) ----
#pragma unroll
        for (int kk = 0; kk < 4; kk++) {
            frag a0 = *reinterpret_cast<const frag*>(&P[buf][lm][kk * 32 + q * 8]);
            frag a1 = *reinterpret_cast<const frag*>(&P[buf][16 + lm][kk * 32 + q * 8]);
#pragma unroll
            for (int nt = 0; nt < 4; nt++) {
                frag b = *reinterpret_cast<const frag*>(brow[nt] + jc + kk * 32);
                acc[0][nt] = __builtin_amdgcn_mfma_f32_16x16x32_bf16(a0, b, acc[0][nt], 0, 0, 0);
                acc[1][nt] = __builtin_amdgcn_mfma_f32_16x16x32_bf16(a1, b, acc[1][nt], 0, 0, 0);
            }
        }
        // single barrier per chunk: next build writes buf^1; buf rewritten only after
        // the NEXT chunk's barrier, which follows every wave's reads of buf.
    }

    // denom partial: builder threads with same m are lanes m*8+cg -> reduce over cg
    float v = dsum;
    v += __shfl_xor(v, 1); v += __shfl_xor(v, 2); v += __shfl_xor(v, 4);
    if (cg == 0) denom4[(size_t)q4 * NN + i0 + m] = v;

    // U4 partial: plain stores (no atomics)
    float* Ub = U4 + (size_t)q4 * NN * HID;
#pragma unroll
    for (int h = 0; h < 2; h++)
#pragma unroll
        for (int nt = 0; nt < 4; nt++)
#pragma unroll
            for (int r = 0; r < 4; r++)
                Ub[(size_t)(i0 + h * 16 + q * 4 + r) * HID + w * 64 + nt * 16 + lm] = acc[h][nt][r];
}

// ---------------- normalize: out = (sum_q U4) / (sum_q denom4) ----------------
__global__ __launch_bounds__(256) void k_norm(const float* __restrict__ U4,
                                              const float* __restrict__ denom4,
                                              float* __restrict__ out) {
    int i = blockIdx.x, t = threadIdx.x;
    size_t S = (size_t)NN * HID;
    size_t base = (size_t)i * HID + t;
    float u = U4[base] + U4[base + S] + U4[base + 2 * S] + U4[base + 3 * S];
    float d = denom4[i] + denom4[i + NN] + denom4[i + 2 * NN] + denom4[i + 3 * NN];
    out[base] = (d != 0.f) ? u / d : 0.f;
}

extern "C" void kernel_launch(void* const* d_in, const int* in_sizes, int n_in,
                              void* d_out, int out_size, void* d_ws, size_t ws_size,
                              hipStream_t stream) {
    const float* X      = (const float*)d_in[0];   // 6144x1024
    const float* W      = (const float*)d_in[1];   // 1024x256
    const float* a_edge = (const float*)d_in[2];   // 512
    const int*   adj    = (const int*)d_in[3];     // 6144x6144
    float* out = (float*)d_out;

    float* U4     = (float*)d_ws;                          // 4*NN*HID f32 (25.2 MB)
    float* denom4 = U4 + (size_t)4 * NN * HID;             // 4*NN
    float* s1     = denom4 + (size_t)4 * NN;               // NN
    float* s2     = s1 + NN;                               // NN
    unsigned short* hT = (unsigned short*)(s2 + NN);       // HID*NN bf16 (3.1 MB)
    unsigned short* Wt = hT + (size_t)HID * NN;            // HID*INPUT bf16 (0.5 MB)

    hipMemsetAsync(s1, 0, 2 * NN * sizeof(float), stream);
    k_convert_w<<<INPUT * HID / 256, 256, 0, stream>>>(W, Wt);
    k_gemm1<<<dim3(NN / 32, HID / 64), 256, 0, stream>>>(X, Wt, a_edge, hT, s1, s2);
    k_attn<<<dim3(NN / 32, 4), 256, 0, stream>>>(adj, s1, s2, hT, U4, denom4);
    k_norm<<<NN, 256, 0, stream>>>(U4, denom4, out);
}